// Round 14
// baseline (2222.213 us; speedup 1.0000x reference)
//
#include <hip/hip_runtime.h>
#include <hip/hip_bf16.h>

// ---------------------------------------------------------------------------
// Sophie on MI355X, round 14 = R13 (best, 2189us) + coalesced co-READ path:
// the LSTM epilogue staged coB through LDS with bf16x8 loads (R12 fixed only
// the stores; the scattered 2-byte co reads were the last transaction-
// amplified stream).
// ---------------------------------------------------------------------------

typedef __bf16 bf16x8 __attribute__((ext_vector_type(8)));
typedef float  f32x4  __attribute__((ext_vector_type(4)));

#define KD 512

__device__ __forceinline__ void gl_lds16(const void* g, void* l) {
  __builtin_amdgcn_global_load_lds(
      (const __attribute__((address_space(1))) void*)g,
      (__attribute__((address_space(3))) void*)l, 16, 0, 0);
}
__device__ __forceinline__ float sigm(float x) {
  return __builtin_amdgcn_rcpf(1.f + __expf(-x));
}
__device__ __forceinline__ float tanh_f(float x) {
  return 2.f * __builtin_amdgcn_rcpf(1.f + __expf(-2.f * x)) - 1.f;
}
__device__ __forceinline__ float sel4(f32x4 v, int i) {
  float a = (i & 1) ? v[1] : v[0];
  float b = (i & 1) ? v[3] : v[2];
  return (i & 2) ? b : a;
}
__device__ __forceinline__ float pick(int m, float o0, float o1, float o2, float o3) {
  float a = (m & 1) ? o1 : o0;
  float b = (m & 1) ? o3 : o2;
  return (m & 2) ? b : a;
}

struct SP {
  const unsigned short* Wp;        // [224 ntg][64 kg][16 nn][8 j]: gates|wk|wv|wq
  unsigned short* A0; unsigned short* A1;   // [4224][512] bf16
  __bf16* Zb0; __bf16* Zb1;        // [4096][1024] bf16: k|v bias-folded
  float* q0; float* q1;            // [512] fp32 q bias-folded
  __bf16* coB;                     // [4224][512] bf16 cell state
  float* ht;                       // [65][512]
  const float* biasz;              // [1536] bk|bv|bq
  const float4* bs4; const float4* w04; const float4* w14;
  const float* others; const float* target;
  const float* scene; const float* out_w; const float* out_b;
  float* part; unsigned int* cnt;
  float* out;
};

// ---------------------------------------------------------------------------
// One 128x256 GEMM tile for step p + fused epilogue.
// ---------------------------------------------------------------------------
__device__ void do_gemm(const SP& P, int p, int bm, int bn)
{
  __shared__ __align__(16) char aLds[2][128 * 64 * 2];   // 32 KB

  const int tid = threadIdx.x, wave = tid >> 6, lane = tid & 63;
  const unsigned short* A = (p & 1) ? P.A1 : P.A0;
  __bf16* An = (__bf16*)((p & 1) ? P.A0 : P.A1);
  __bf16* Zb = (p & 1) ? P.Zb1 : P.Zb0;
  float* qv  = (p & 1) ? P.q1 : P.q0;
  const int tin = (p + 1 < 31) ? (p + 1) : 31;
  const int tc  = (p + 1 < 63) ? (p + 1) : 63;
  const float* op = P.others + (size_t)tin * 8192;
  const float* tp = P.target + tc * 2;
  float* htn = P.ht + (size_t)(p + 1) * 512;

  const int m0 = bm * 128;
  const int l15 = lane & 15, lq = lane >> 4;

  int aRow[4], aOff[4], ldsOff[4];
#pragma unroll
  for (int j = 0; j < 4; ++j) {
    int chunk = j * 4 + wave;
    int r = chunk * 8 + (lane >> 3), ch = lane & 7;
    aRow[j]   = m0 + r;
    aOff[j]   = (ch ^ (r & 7)) * 8;
    ldsOff[j] = chunk * 1024;
  }
  const unsigned short* bBase =
      P.Wp + (size_t)(bn * 16 + wave * 4) * 8192 + lq * 128 + l15 * 8;

  f32x4 acc[8][4];
#pragma unroll
  for (int i = 0; i < 8; ++i)
#pragma unroll
    for (int j = 0; j < 4; ++j) acc[i][j] = f32x4{0.f, 0.f, 0.f, 0.f};

  bf16x8 bCur[4], bNext[4];

#pragma unroll
  for (int j = 0; j < 4; ++j)
    gl_lds16(A + (size_t)aRow[j] * KD + aOff[j], aLds[0] + ldsOff[j]);
#pragma unroll
  for (int nt = 0; nt < 4; ++nt)
    bCur[nt] = *(const bf16x8*)(bBase + nt * 8192);     // (it=0, c=0)
  __syncthreads();

  for (int it = 0; it < 8; ++it) {
    if (it < 7) {
      const int k1 = (it + 1) * 64;
#pragma unroll
      for (int j = 0; j < 4; ++j)
        gl_lds16(A + (size_t)aRow[j] * KD + k1 + aOff[j],
                 aLds[(it + 1) & 1] + ldsOff[j]);
    }
    const char* buf = aLds[it & 1];
#pragma unroll
    for (int c = 0; c < 2; ++c) {
      const bool hasNext = !(it == 7 && c == 1);
      if (hasNext) {
        const int nit = (c == 0) ? it : it + 1;
        const int nc  = (c == 0) ? 1 : 0;
#pragma unroll
        for (int nt = 0; nt < 4; ++nt)
          bNext[nt] = *(const bf16x8*)(bBase + nt * 8192 + nit * 1024 + nc * 512);
      }
      bf16x8 af[8];
#pragma unroll
      for (int mt = 0; mt < 8; ++mt) {
        int row = mt * 16 + l15;
        int ch16 = (c * 4 + lq) ^ (row & 7);
        af[mt] = *(const bf16x8*)(buf + row * 128 + ch16 * 16);
      }
#pragma unroll
      for (int mt = 0; mt < 8; ++mt)
#pragma unroll
        for (int nt = 0; nt < 4; ++nt)
          acc[mt][nt] = __builtin_amdgcn_mfma_f32_16x16x32_bf16(
              af[mt], bCur[nt], acc[mt][nt], 0, 0, 0);
      if (hasNext) {
#pragma unroll
        for (int nt = 0; nt < 4; ++nt) bCur[nt] = bNext[nt];
      }
    }
    __syncthreads();
  }
  // K-loop done; aLds free for epilogue staging.

  const int rq = lq * 4;

  if (bn >= 12) {
    // ---- q epilogue: row 4096 only (bm==32 tiles) ----
    if (lq == 0) {
#pragma unroll
      for (int nt = 0; nt < 4; ++nt) {
        int qcol = (bn - 12) * 256 + wave * 64 + nt * 16 + l15;
        qv[qcol] = acc[0][nt][0] + P.biasz[1024 + qcol];
      }
    }
    return;
  }

  if (bn >= 8) {
    // ---- k/v epilogue: LDS transpose -> coalesced 16B stores, 2 halves ----
    __bf16* zT = (__bf16*)aLds;          // [64][256] per half
    const int zbase = (bn - 8) * 256;
    float bias[4];
#pragma unroll
    for (int nt = 0; nt < 4; ++nt)
      bias[nt] = P.biasz[zbase + wave * 64 + nt * 16 + l15];
#pragma unroll
    for (int half = 0; half < 2; ++half) {
#pragma unroll
      for (int mt2 = 0; mt2 < 4; ++mt2) {
        int mt = half * 4 + mt2;
#pragma unroll
        for (int nt = 0; nt < 4; ++nt) {
          int ulocal = wave * 64 + nt * 16 + l15;
#pragma unroll
          for (int r = 0; r < 4; ++r) {
            int rloc = mt2 * 16 + rq + r;
            zT[rloc * 256 + ulocal] = (__bf16)(acc[mt][nt][r] + bias[nt]);
          }
        }
      }
      __syncthreads();
      const bf16x8* zc = (const bf16x8*)zT;
#pragma unroll
      for (int i = 0; i < 8; ++i) {
        int idx = i * 256 + tid;
        int rloc = idx >> 5, c8 = idx & 31;
        *(bf16x8*)(Zb + (size_t)(m0 + half * 64 + rloc) * 1024 + zbase + c8 * 8) = zc[idx];
      }
      __syncthreads();
    }
    return;
  }

  // ---- gate epilogue: fused LSTM cell ----
  const int rho = lane & 3, usel = (lane >> 2) & 3;
  const int u0 = bn * 64 + wave * 16;
  float4 bsv[4], w0v[4], w1v[4];
  int uu[4];
#pragma unroll
  for (int nt = 0; nt < 4; ++nt) {
    uu[nt]  = u0 + nt * 4 + usel;
    bsv[nt] = P.bs4[uu[nt]];
    w0v[nt] = P.w04[uu[nt]];
    w1v[nt] = P.w14[uu[nt]];
  }

  if (bm < 32) {
    __bf16* hT = (__bf16*)aLds[0];       // [128][64] h out
    __bf16* cT = (__bf16*)aLds[1];       // [128][64] co staged in / cn out
    // coalesced co-tile load (the R14 change: kill scattered 2B co reads)
    bf16x8* cT8 = (bf16x8*)cT;
#pragma unroll
    for (int i = 0; i < 4; ++i) {
      int idx = i * 256 + tid;           // 0..1023
      int rloc = idx >> 3, c8 = idx & 7;
      cT8[idx] = *(const bf16x8*)(P.coB + (size_t)(m0 + rloc) * 512 + bn * 64 + c8 * 8);
    }
    __syncthreads();
#pragma unroll
    for (int mt = 0; mt < 8; ++mt) {
      int rloc = mt * 16 + rq + rho;
      int row  = m0 + rloc;
      float x0 = op[2 * row], x1 = op[2 * row + 1];
#pragma unroll
      for (int nt = 0; nt < 4; ++nt) {
        f32x4 v = acc[mt][nt];
        float own = sel4(v, rho);
        float r1  = __shfl_xor(sel4(v, rho ^ 1), 1, 64);
        float r2  = __shfl_xor(sel4(v, rho ^ 2), 2, 64);
        float r3  = __shfl_xor(sel4(v, rho ^ 3), 3, 64);
        float g0 = pick(rho,     own, r1, r2, r3);
        float g1 = pick(rho ^ 1, own, r1, r2, r3);
        float g2 = pick(rho ^ 2, own, r1, r2, r3);
        float g3 = pick(rho ^ 3, own, r1, r2, r3);
        float4 bs = bsv[nt], w0 = w0v[nt], w1 = w1v[nt];
        float p0 = g0 + bs.x + w0.x * x0 + w1.x * x1;
        float p1 = g1 + bs.y + w0.y * x0 + w1.y * x1;
        float p2 = g2 + bs.z + w0.z * x0 + w1.z * x1;
        float p3 = g3 + bs.w + w0.w * x0 + w1.w * x1;
        int ulocal = uu[nt] - bn * 64;
        float c_old = (float)cT[rloc * 64 + ulocal];
        float ii = sigm(p0), ff = sigm(p1), gg = tanh_f(p2), oo = sigm(p3);
        float cn = ff * c_old + ii * gg;
        float h  = oo * tanh_f(cn);
        hT[rloc * 64 + ulocal] = (__bf16)h;
        cT[rloc * 64 + ulocal] = (__bf16)cn;
      }
    }
    __syncthreads();
    const bf16x8* hc = (const bf16x8*)hT;
    const bf16x8* cc = (const bf16x8*)cT;
#pragma unroll
    for (int i = 0; i < 4; ++i) {
      int idx = i * 256 + tid;
      int rloc = idx >> 3, c8 = idx & 7;
      size_t base = (size_t)(m0 + rloc) * 512 + bn * 64 + c8 * 8;
      *(bf16x8*)(An + base)    = hc[idx];
      *(bf16x8*)(P.coB + base) = cc[idx];
    }
    return;
  }

  // bm == 32: only row 4096 valid (tiny volume, scattered ok)
#pragma unroll
  for (int mt = 0; mt < 8; ++mt) {
    int row = m0 + mt * 16 + rq + rho;
    bool act = row <= 4096;
    float x0 = 0.f, x1 = 0.f;
    if (act) {
      if (row < 4096) { x0 = op[2 * row]; x1 = op[2 * row + 1]; }
      else            { x0 = tp[0];       x1 = tp[1]; }
    }
#pragma unroll
    for (int nt = 0; nt < 4; ++nt) {
      f32x4 v = acc[mt][nt];
      float own = sel4(v, rho);
      float r1  = __shfl_xor(sel4(v, rho ^ 1), 1, 64);
      float r2  = __shfl_xor(sel4(v, rho ^ 2), 2, 64);
      float r3  = __shfl_xor(sel4(v, rho ^ 3), 3, 64);
      float g0 = pick(rho,     own, r1, r2, r3);
      float g1 = pick(rho ^ 1, own, r1, r2, r3);
      float g2 = pick(rho ^ 2, own, r1, r2, r3);
      float g3 = pick(rho ^ 3, own, r1, r2, r3);
      if (act) {
        float4 bs = bsv[nt], w0 = w0v[nt], w1 = w1v[nt];
        float p0 = g0 + bs.x + w0.x * x0 + w1.x * x1;
        float p1 = g1 + bs.y + w0.y * x0 + w1.y * x1;
        float p2 = g2 + bs.z + w0.z * x0 + w1.z * x1;
        float p3 = g3 + bs.w + w0.w * x0 + w1.w * x1;
        int u = uu[nt];
        size_t ci = (size_t)row * 512 + u;
        float c_old = (float)P.coB[ci];
        float ii = sigm(p0), ff = sigm(p1), gg = tanh_f(p2), oo = sigm(p3);
        float cn = ff * c_old + ii * gg;
        float h  = oo * tanh_f(cn);
        P.coB[ci] = (__bf16)cn;
        An[ci] = (__bf16)h;
        if (row == 4096) htn[u] = h;
      }
    }
  }
}

// ---------------------------------------------------------------------------
// Attention for step p, task b (64 tasks x 64 rows) + last-done finalize.
// ---------------------------------------------------------------------------
__device__ void do_att(const SP& P, int p, int b)
{
  __shared__ __align__(16) float qs[512];
  __shared__ float red[256];
  __shared__ float red2[256];
  __shared__ float es[64];
  __shared__ unsigned int sOld;
  const int t = threadIdx.x;
  const __bf16* Zb = (p & 1) ? P.Zb1 : P.Zb0;
  const float* qv  = (p & 1) ? P.q1 : P.q0;
  const float* ht  = P.ht + (size_t)p * 512;

  for (int c = t; c < 512; c += 256) qs[c] = qv[c];
  __syncthreads();

  const int r0 = b * 64, rl = t >> 2, p4 = t & 3;
  const bf16x8* krow = (const bf16x8*)(Zb + (size_t)(r0 + rl) * 1024);
  float a = 0.f;
  for (int i = p4; i < 64; i += 4) {
    bf16x8 kk = krow[i];
    const float* qq = qs + i * 8;
#pragma unroll
    for (int j = 0; j < 8; ++j) a += (float)kk[j] * qq[j];
  }
  red[t] = a;
  __syncthreads();
  if (t < 64)
    es[t] = __expf((red[4 * t] + red[4 * t + 1] + red[4 * t + 2] + red[4 * t + 3]) *
                   0.04419417382415922f);
  __syncthreads();

  float s0 = 0.f, s1 = 0.f;
  for (int r = 0; r < 64; ++r) {
    const __bf16* vr = Zb + (size_t)(r0 + r) * 1024 + 512;
    float e = es[r];
    s0 += e * (float)vr[t];
    s1 += e * (float)vr[t + 256];
  }
  P.part[b * 513 + t] = s0;
  P.part[b * 513 + 256 + t] = s1;
  if (t == 0) {
    float se = 0.f;
#pragma unroll
    for (int r = 0; r < 64; ++r) se += es[r];
    P.part[b * 513 + 512] = se;
  }
  __threadfence();
  __syncthreads();
  if (t == 0) sOld = atomicAdd(P.cnt, 1u);
  __syncthreads();
  if (sOld == 63) {
    __threadfence();
    float s = 0.f, s2 = 0.f, se = 0.f;
    for (int bb = 0; bb < 64; ++bb) {
      s  += P.part[bb * 513 + t];
      s2 += P.part[bb * 513 + 256 + t];
      se += P.part[bb * 513 + 512];
    }
    float inv = 1.f / se;
    float va = ht[t] + s * inv + P.scene[t];
    float vb = ht[t + 256] + s2 * inv + P.scene[t + 256];
    red[t]  = va * P.out_w[t]       + vb * P.out_w[t + 256];
    red2[t] = va * P.out_w[512 + t] + vb * P.out_w[768 + t];
    __syncthreads();
    for (int st = 128; st > 0; st >>= 1) {
      if (t < st) { red[t] += red[t + st]; red2[t] += red2[t + st]; }
      __syncthreads();
    }
    if (t == 0) {
      P.out[2 * p]     = red[0]  + P.out_b[0];
      P.out[2 * p + 1] = red2[0] + P.out_b[1];
      *P.cnt = 0;
    }
  }
}

// ---------------------------------------------------------------------------
// Step dispatch: 458 blocks (R13 decode).
// ---------------------------------------------------------------------------
__global__ __launch_bounds__(256, 2) void step_kernel(SP P, int p)
{
  const int b = blockIdx.x;
  if (b < 384) {
    int x = b & 7, s = b >> 3;
    do_gemm(P, p, x + 8 * (s / 12), s % 12);
  } else if (b < 448) {
    int x = b & 7, idx = (b >> 3) - 48;
    int a = 2 * (x + 8 * (idx >> 1)) + (idx & 1);
    if (p >= 1) do_att(P, p - 1, a);
  } else {
    int ti = b - 448;
    int bn = (ti < 8) ? ti : (12 + (ti - 8));
    do_gemm(P, p, 32, bn);
  }
}

__global__ __launch_bounds__(256) void att_step(SP P, int p) {
  do_att(P, p, blockIdx.x);
}

// ---------------------------------------------------------------------------
// Prep kernels (unchanged).
// ---------------------------------------------------------------------------
__global__ __launch_bounds__(256) void init_state(
    const float* __restrict__ others0, const float* __restrict__ target0,
    const float* __restrict__ w_ih, const float* __restrict__ b_ih,
    const float* __restrict__ b_hh,
    __bf16* __restrict__ coB, __bf16* __restrict__ A0, float* __restrict__ ht0,
    unsigned int* __restrict__ cnt)
{
  int g = blockIdx.x * 256 + threadIdx.x;
  if (g == 0) *cnt = 0u;
  if (g >= 4097 * 512) return;
  int r = g >> 9, j = g & 511;
  float x0, x1;
  if (r < 4096) { x0 = others0[2 * r]; x1 = others0[2 * r + 1]; }
  else          { x0 = target0[0];     x1 = target0[1]; }
  float pre[4];
#pragma unroll
  for (int gg = 0; gg < 4; ++gg) {
    int n = gg * 512 + j;
    pre[gg] = b_ih[n] + b_hh[n] + w_ih[2 * n] * x0 + w_ih[2 * n + 1] * x1;
  }
  float cn = sigm(pre[0]) * tanh_f(pre[2]);
  float h  = sigm(pre[3]) * tanh_f(cn);
  coB[g] = (__bf16)cn;
  A0[g] = (__bf16)h;
  if (r == 4096) ht0[j] = h;
}

__global__ __launch_bounds__(256) void pack_w(
    const float* __restrict__ w_hh, const float* __restrict__ wk,
    const float* __restrict__ wv,   const float* __restrict__ wq,
    __bf16* __restrict__ Wp)
{
  int o = blockIdx.x * 256 + threadIdx.x;   // 1,835,008
  int j = o & 7, nn = (o >> 3) & 15, kg = (o >> 7) & 63, ntg = o >> 13;
  int n = ntg * 16 + nn, k = kg * 8 + j;
  float v;
  if (n < 2048)      { int u = n >> 2, g = n & 3; v = w_hh[(g * 512 + u) * 512 + k]; }
  else if (n < 2560) v = wk[(n - 2048) * 512 + k];
  else if (n < 3072) v = wv[(n - 2560) * 512 + k];
  else               v = wq[(n - 3072) * 512 + k];
  Wp[o] = (__bf16)v;
}

__global__ __launch_bounds__(256) void pack_misc(
    const float* __restrict__ b_ih, const float* __restrict__ b_hh,
    const float* __restrict__ w_ih,
    const float* __restrict__ bk, const float* __restrict__ bv,
    const float* __restrict__ bq,
    float* __restrict__ bs, float* __restrict__ w0, float* __restrict__ w1,
    float* __restrict__ biasz)
{
  int i = blockIdx.x * 256 + threadIdx.x;
  if (i < 2048) {
    int u = i >> 2, g = i & 3, n = g * 512 + u;
    bs[i] = b_ih[n] + b_hh[n];
    w0[i] = w_ih[2 * n];
    w1[i] = w_ih[2 * n + 1];
  } else if (i < 2048 + 1536) {
    int z = i - 2048;
    biasz[z] = (z < 512) ? bk[z] : (z < 1024 ? bv[z - 512] : bq[z - 1024]);
  }
}

__global__ __launch_bounds__(256) void scene1_kernel(
    const int* __restrict__ map, const float* __restrict__ emb,
    const float* __restrict__ w1, const float* __restrict__ b1,
    float* __restrict__ out1)
{
  __shared__ float wl[576];
  __shared__ float bl[16];
  const int t = threadIdx.x;
  for (int i = t; i < 576; i += 256) wl[i] = w1[i];
  if (t < 16) bl[t] = b1[t];
  __syncthreads();
  const int y = blockIdx.x, x = t;
  float nb[4][9];
#pragma unroll
  for (int dy = 0; dy < 3; ++dy)
#pragma unroll
    for (int dx = 0; dx < 3; ++dx) {
      int yy = y + dy - 1, xx = x + dx - 1;
      bool ok = (yy >= 0 && yy < 256 && xx >= 0 && xx < 256);
      int m = ok ? map[yy * 256 + xx] : 0;
#pragma unroll
      for (int c = 0; c < 4; ++c)
        nb[c][dy * 3 + dx] = ok ? emb[m * 4 + c] : 0.f;
    }
  for (int oc = 0; oc < 16; ++oc) {
    float a = bl[oc];
#pragma unroll
    for (int c = 0; c < 4; ++c)
#pragma unroll
      for (int k = 0; k < 9; ++k) a += wl[(oc * 4 + c) * 9 + k] * nb[c][k];
    out1[oc * 65536 + y * 256 + x] = fmaxf(a, 0.f);
  }
}

__global__ __launch_bounds__(256) void scene2_kernel(
    const float* __restrict__ out1, const float* __restrict__ w2,
    const float* __restrict__ b2, float* __restrict__ rowpart)
{
  __shared__ float wl[1152];
  __shared__ float lds4[4 * 8];
  const int t = threadIdx.x;
  const int y = blockIdx.x & 255, ocg = blockIdx.x >> 8;
  for (int i = t; i < 1152; i += 256) wl[i] = w2[ocg * 1152 + i];
  __syncthreads();
  const int x = t;
  float acc[8];
#pragma unroll
  for (int o = 0; o < 8; ++o) acc[o] = b2[ocg * 8 + o];
  for (int ic = 0; ic < 16; ++ic) {
    float nb[9];
#pragma unroll
    for (int dy = 0; dy < 3; ++dy)
#pragma unroll
      for (int dx = 0; dx < 3; ++dx) {
        int yy = y + dy - 1, xx = x + dx - 1;
        bool ok = (yy >= 0 && yy < 256 && xx >= 0 && xx < 256);
        nb[dy * 3 + dx] = ok ? out1[ic * 65536 + yy * 256 + xx] : 0.f;
      }
#pragma unroll
    for (int o = 0; o < 8; ++o) {
      const float* w = &wl[(o * 16 + ic) * 9];
#pragma unroll
      for (int k = 0; k < 9; ++k) acc[o] += w[k] * nb[k];
    }
  }
  const int wave = t >> 6, lane = t & 63;
#pragma unroll
  for (int o = 0; o < 8; ++o) {
    float v = fmaxf(acc[o], 0.f);
#pragma unroll
    for (int m = 1; m < 64; m <<= 1) v += __shfl_xor(v, m, 64);
    if (lane == 0) lds4[wave * 8 + o] = v;
  }
  __syncthreads();
  if (t < 8)
    rowpart[y * 32 + ocg * 8 + t] = lds4[t] + lds4[8 + t] + lds4[16 + t] + lds4[24 + t];
}

__global__ __launch_bounds__(512) void scene3_kernel(
    const float* __restrict__ rowpart, const float* __restrict__ fcw,
    const float* __restrict__ fcb, float* __restrict__ scene)
{
  __shared__ float mean[32];
  const int t = threadIdx.x;
  if (t < 32) {
    float s = 0.f;
    for (int y = 0; y < 256; ++y) s += rowpart[y * 32 + t];
    mean[t] = s * (1.f / 65536.f);
  }
  __syncthreads();
  float a = fcb[t];
#pragma unroll
  for (int c = 0; c < 32; ++c) a += mean[c] * fcw[t * 32 + c];
  scene[t] = a;
}

// ---------------------------------------------------------------------------
extern "C" void kernel_launch(void* const* d_in, const int* in_sizes, int n_in,
                              void* d_out, int out_size, void* d_ws, size_t ws_size,
                              hipStream_t stream) {
  const float* target    = (const float*)d_in[0];
  const float* others    = (const float*)d_in[1];
  const int*   scene_map = (const int*)d_in[2];
  const float* emb       = (const float*)d_in[3];
  const float* c1w       = (const float*)d_in[4];
  const float* c1b       = (const float*)d_in[5];
  const float* c2w       = (const float*)d_in[6];
  const float* c2b       = (const float*)d_in[7];
  const float* fcw       = (const float*)d_in[8];
  const float* fcb       = (const float*)d_in[9];
  const float* w_ih      = (const float*)d_in[10];
  const float* w_hh      = (const float*)d_in[11];
  const float* b_ih      = (const float*)d_in[12];
  const float* b_hh      = (const float*)d_in[13];
  const float* wq        = (const float*)d_in[14];
  const float* bq        = (const float*)d_in[15];
  const float* wk        = (const float*)d_in[16];
  const float* bk        = (const float*)d_in[17];
  const float* wv        = (const float*)d_in[18];
  const float* bv        = (const float*)d_in[19];
  const float* out_w     = (const float*)d_in[20];
  const float* out_b     = (const float*)d_in[21];
  float* out = (float*)d_out;

  char* ws = (char*)d_ws;
  size_t off = 0;
  auto alloc = [&](size_t bytes) { size_t o = off; off += (bytes + 255) & ~(size_t)255; return o; };
  __bf16* Zb0   = (__bf16*)(ws + alloc((size_t)4096 * 1024 * 2));
  __bf16* Zb1   = (__bf16*)(ws + alloc((size_t)4096 * 1024 * 2));
  float*  q0    = (float*)(ws + alloc(512 * 4));
  float*  q1    = (float*)(ws + alloc(512 * 4));
  __bf16* Wp    = (__bf16*)(ws + alloc((size_t)1835008 * 2));
  __bf16* A0    = (__bf16*)(ws + alloc((size_t)4224 * 512 * 2));
  __bf16* A1    = (__bf16*)(ws + alloc((size_t)4224 * 512 * 2));
  __bf16* coB   = (__bf16*)(ws + alloc((size_t)4224 * 512 * 2));
  float*  ht    = (float*)(ws + alloc((size_t)65 * 512 * 4));
  float*  scene = (float*)(ws + alloc(2048));
  float*  part  = (float*)(ws + alloc(64 * 513 * 4));
  unsigned int* cnt = (unsigned int*)(ws + alloc(256));
  float*  bs    = (float*)(ws + alloc(2048 * 4));
  float*  w0p   = (float*)(ws + alloc(2048 * 4));
  float*  w1p   = (float*)(ws + alloc(2048 * 4));
  float*  biasz = (float*)(ws + alloc(1536 * 4));
  float*  out1  = (float*)(ws + alloc((size_t)16 * 65536 * 4));
  float*  rowp  = (float*)(ws + alloc(256 * 32 * 4));

  pack_w<<<7168, 256, 0, stream>>>(w_hh, wk, wv, wq, Wp);
  pack_misc<<<14, 256, 0, stream>>>(b_ih, b_hh, w_ih, bk, bv, bq, bs, w0p, w1p, biasz);
  scene1_kernel<<<256, 256, 0, stream>>>(scene_map, emb, c1w, c1b, out1);
  scene2_kernel<<<1024, 256, 0, stream>>>(out1, c2w, c2b, rowp);
  scene3_kernel<<<1, 512, 0, stream>>>(rowp, fcw, fcb, scene);
  init_state<<<8194, 256, 0, stream>>>(others, target, w_ih, b_ih, b_hh, coB, A0, ht, cnt);

  SP hp;
  hp.Wp = (const unsigned short*)Wp;
  hp.A0 = (unsigned short*)A0; hp.A1 = (unsigned short*)A1;
  hp.Zb0 = Zb0; hp.Zb1 = Zb1;
  hp.q0 = q0; hp.q1 = q1;
  hp.coB = coB; hp.ht = ht;
  hp.biasz = biasz;
  hp.bs4 = (const float4*)bs; hp.w04 = (const float4*)w0p; hp.w14 = (const float4*)w1p;
  hp.others = others; hp.target = target;
  hp.scene = scene; hp.out_w = out_w; hp.out_b = out_b;
  hp.part = part; hp.cnt = cnt;
  hp.out = out;

  for (int p = 0; p < 64; ++p)
    step_kernel<<<458, 256, 0, stream>>>(hp, p);
  att_step<<<64, 256, 0, stream>>>(hp, 63);
}

// Round 15
// 2183.421 us; speedup vs baseline: 1.0178x; 1.0178x over previous
//
#include <hip/hip_runtime.h>
#include <hip/hip_bf16.h>

// ---------------------------------------------------------------------------
// Sophie on MI355X, round 15 = R13 (best, 2189us) with BK=128 K-loop:
// half the barrier-drains (4 vs 8), double staging MLP (8 global_load_lds in
// flight/wave), 2x32KB LDS double buffer (still 2 blocks/CU).
// R14's co-read LDS staging reverted (measured neutral).
// ---------------------------------------------------------------------------

typedef __bf16 bf16x8 __attribute__((ext_vector_type(8)));
typedef float  f32x4  __attribute__((ext_vector_type(4)));

#define KD 512

__device__ __forceinline__ void gl_lds16(const void* g, void* l) {
  __builtin_amdgcn_global_load_lds(
      (const __attribute__((address_space(1))) void*)g,
      (__attribute__((address_space(3))) void*)l, 16, 0, 0);
}
__device__ __forceinline__ float sigm(float x) {
  return __builtin_amdgcn_rcpf(1.f + __expf(-x));
}
__device__ __forceinline__ float tanh_f(float x) {
  return 2.f * __builtin_amdgcn_rcpf(1.f + __expf(-2.f * x)) - 1.f;
}
__device__ __forceinline__ float sel4(f32x4 v, int i) {
  float a = (i & 1) ? v[1] : v[0];
  float b = (i & 1) ? v[3] : v[2];
  return (i & 2) ? b : a;
}
__device__ __forceinline__ float pick(int m, float o0, float o1, float o2, float o3) {
  float a = (m & 1) ? o1 : o0;
  float b = (m & 1) ? o3 : o2;
  return (m & 2) ? b : a;
}

struct SP {
  const unsigned short* Wp;        // [224 ntg][64 kg][16 nn][8 j]: gates|wk|wv|wq
  unsigned short* A0; unsigned short* A1;   // [4224][512] bf16
  __bf16* Zb0; __bf16* Zb1;        // [4096][1024] bf16: k|v bias-folded
  float* q0; float* q1;            // [512] fp32 q bias-folded
  __bf16* coB;                     // [4224][512] bf16 cell state
  float* ht;                       // [65][512]
  const float* biasz;              // [1536] bk|bv|bq
  const float4* bs4; const float4* w04; const float4* w14;
  const float* others; const float* target;
  const float* scene; const float* out_w; const float* out_b;
  float* part; unsigned int* cnt;
  float* out;
};

// ---------------------------------------------------------------------------
// One 128x256 GEMM tile for step p + fused epilogue. BK=128.
// LDS buffer layout: [row 0..127][granule 0..15] where LDS granule g of row r
// holds global k-granule (g ^ (r & 15)) (16B granules, 8 bf16 each).
// ---------------------------------------------------------------------------
__device__ void do_gemm(const SP& P, int p, int bm, int bn)
{
  __shared__ __align__(16) char aLds[2][128 * 128 * 2];   // 2 x 32 KB

  const int tid = threadIdx.x, wave = tid >> 6, lane = tid & 63;
  const unsigned short* A = (p & 1) ? P.A1 : P.A0;
  __bf16* An = (__bf16*)((p & 1) ? P.A0 : P.A1);
  __bf16* Zb = (p & 1) ? P.Zb1 : P.Zb0;
  float* qv  = (p & 1) ? P.q1 : P.q0;
  const int tin = (p + 1 < 31) ? (p + 1) : 31;
  const int tc  = (p + 1 < 63) ? (p + 1) : 63;
  const float* op = P.others + (size_t)tin * 8192;
  const float* tp = P.target + tc * 2;
  float* htn = P.ht + (size_t)(p + 1) * 512;

  const int m0 = bm * 128;
  const int l15 = lane & 15, lq = lane >> 4;

  // A staging: 32 chunks of 1KB per 128-wide K-iter; wave stages 8 chunks.
  // chunk = j*4+wave covers rows [chunk*4, chunk*4+4), all 16 granules.
  int aRow[8], aOff[8], ldsOff[8];
#pragma unroll
  for (int j = 0; j < 8; ++j) {
    int chunk = j * 4 + wave;                 // 0..31
    int r = chunk * 4 + (lane >> 4);          // row local 0..127
    int ch = lane & 15;                       // LDS granule slot
    aRow[j]   = m0 + r;
    aOff[j]   = (ch ^ (r & 15)) * 8;          // global elem offset in row
    ldsOff[j] = chunk * 1024;
  }
  const unsigned short* bBase =
      P.Wp + (size_t)(bn * 16 + wave * 4) * 8192 + lq * 128 + l15 * 8;

  f32x4 acc[8][4];
#pragma unroll
  for (int i = 0; i < 8; ++i)
#pragma unroll
    for (int j = 0; j < 4; ++j) acc[i][j] = f32x4{0.f, 0.f, 0.f, 0.f};

  bf16x8 bCur[4], bNext[4];

#pragma unroll
  for (int j = 0; j < 8; ++j)
    gl_lds16(A + (size_t)aRow[j] * KD + aOff[j], aLds[0] + ldsOff[j]);
#pragma unroll
  for (int nt = 0; nt < 4; ++nt)
    bCur[nt] = *(const bf16x8*)(bBase + nt * 8192);     // kc = 0
  __syncthreads();

  for (int it = 0; it < 4; ++it) {
    if (it < 3) {
      const int k1 = (it + 1) * 128;
#pragma unroll
      for (int j = 0; j < 8; ++j)
        gl_lds16(A + (size_t)aRow[j] * KD + k1 + aOff[j],
                 aLds[(it + 1) & 1] + ldsOff[j]);
    }
    const char* buf = aLds[it & 1];
#pragma unroll
    for (int c = 0; c < 4; ++c) {
      const bool hasNext = !(it == 3 && c == 3);
      if (hasNext) {
        const int nkc = it * 4 + c + 1;       // next K-chunk (K=32 units)
#pragma unroll
        for (int nt = 0; nt < 4; ++nt)
          bNext[nt] = *(const bf16x8*)(bBase + nt * 8192 + nkc * 512);
      }
      bf16x8 af[8];
#pragma unroll
      for (int mt = 0; mt < 8; ++mt) {
        int row = mt * 16 + l15;
        int g = (c * 4 + lq) ^ (row & 15);
        af[mt] = *(const bf16x8*)(buf + row * 256 + g * 16);
      }
#pragma unroll
      for (int mt = 0; mt < 8; ++mt)
#pragma unroll
        for (int nt = 0; nt < 4; ++nt)
          acc[mt][nt] = __builtin_amdgcn_mfma_f32_16x16x32_bf16(
              af[mt], bCur[nt], acc[mt][nt], 0, 0, 0);
      if (hasNext) {
#pragma unroll
        for (int nt = 0; nt < 4; ++nt) bCur[nt] = bNext[nt];
      }
    }
    __syncthreads();
  }
  // K-loop done; aLds free for epilogue staging.

  const int rq = lq * 4;

  if (bn >= 12) {
    // ---- q epilogue: row 4096 only (bm==32 tiles) ----
    if (lq == 0) {
#pragma unroll
      for (int nt = 0; nt < 4; ++nt) {
        int qcol = (bn - 12) * 256 + wave * 64 + nt * 16 + l15;
        qv[qcol] = acc[0][nt][0] + P.biasz[1024 + qcol];
      }
    }
    return;
  }

  if (bn >= 8) {
    // ---- k/v epilogue: LDS transpose -> coalesced 16B stores, 2 halves ----
    __bf16* zT = (__bf16*)aLds;          // [64][256] per half (32 KB)
    const int zbase = (bn - 8) * 256;
    float bias[4];
#pragma unroll
    for (int nt = 0; nt < 4; ++nt)
      bias[nt] = P.biasz[zbase + wave * 64 + nt * 16 + l15];
#pragma unroll
    for (int half = 0; half < 2; ++half) {
#pragma unroll
      for (int mt2 = 0; mt2 < 4; ++mt2) {
        int mt = half * 4 + mt2;
#pragma unroll
        for (int nt = 0; nt < 4; ++nt) {
          int ulocal = wave * 64 + nt * 16 + l15;
#pragma unroll
          for (int r = 0; r < 4; ++r) {
            int rloc = mt2 * 16 + rq + r;
            zT[rloc * 256 + ulocal] = (__bf16)(acc[mt][nt][r] + bias[nt]);
          }
        }
      }
      __syncthreads();
      const bf16x8* zc = (const bf16x8*)zT;
#pragma unroll
      for (int i = 0; i < 8; ++i) {
        int idx = i * 256 + tid;
        int rloc = idx >> 5, c8 = idx & 31;
        *(bf16x8*)(Zb + (size_t)(m0 + half * 64 + rloc) * 1024 + zbase + c8 * 8) = zc[idx];
      }
      __syncthreads();
    }
    return;
  }

  // ---- gate epilogue: fused LSTM cell (R13 form) ----
  const int rho = lane & 3, usel = (lane >> 2) & 3;
  const int u0 = bn * 64 + wave * 16;
  float4 bsv[4], w0v[4], w1v[4];
  int uu[4];
#pragma unroll
  for (int nt = 0; nt < 4; ++nt) {
    uu[nt]  = u0 + nt * 4 + usel;
    bsv[nt] = P.bs4[uu[nt]];
    w0v[nt] = P.w04[uu[nt]];
    w1v[nt] = P.w14[uu[nt]];
  }

  if (bm < 32) {
    __bf16* hT = (__bf16*)aLds[0];       // [128][64]
    __bf16* cT = (__bf16*)aLds[1];       // [128][64]
#pragma unroll
    for (int mt = 0; mt < 8; ++mt) {
      int rloc = mt * 16 + rq + rho;
      int row  = m0 + rloc;
      float x0 = op[2 * row], x1 = op[2 * row + 1];
#pragma unroll
      for (int nt = 0; nt < 4; ++nt) {
        f32x4 v = acc[mt][nt];
        float own = sel4(v, rho);
        float r1  = __shfl_xor(sel4(v, rho ^ 1), 1, 64);
        float r2  = __shfl_xor(sel4(v, rho ^ 2), 2, 64);
        float r3  = __shfl_xor(sel4(v, rho ^ 3), 3, 64);
        float g0 = pick(rho,     own, r1, r2, r3);
        float g1 = pick(rho ^ 1, own, r1, r2, r3);
        float g2 = pick(rho ^ 2, own, r1, r2, r3);
        float g3 = pick(rho ^ 3, own, r1, r2, r3);
        float4 bs = bsv[nt], w0 = w0v[nt], w1 = w1v[nt];
        float p0 = g0 + bs.x + w0.x * x0 + w1.x * x1;
        float p1 = g1 + bs.y + w0.y * x0 + w1.y * x1;
        float p2 = g2 + bs.z + w0.z * x0 + w1.z * x1;
        float p3 = g3 + bs.w + w0.w * x0 + w1.w * x1;
        int u = uu[nt];
        size_t ci = (size_t)row * 512 + u;
        float c_old = (float)P.coB[ci];
        float ii = sigm(p0), ff = sigm(p1), gg = tanh_f(p2), oo = sigm(p3);
        float cn = ff * c_old + ii * gg;
        float h  = oo * tanh_f(cn);
        int ulocal = u - bn * 64;
        hT[rloc * 64 + ulocal] = (__bf16)h;
        cT[rloc * 64 + ulocal] = (__bf16)cn;
      }
    }
    __syncthreads();
    const bf16x8* hc = (const bf16x8*)hT;
    const bf16x8* cc = (const bf16x8*)cT;
#pragma unroll
    for (int i = 0; i < 4; ++i) {
      int idx = i * 256 + tid;
      int rloc = idx >> 3, c8 = idx & 7;
      size_t base = (size_t)(m0 + rloc) * 512 + bn * 64 + c8 * 8;
      *(bf16x8*)(An + base)    = hc[idx];
      *(bf16x8*)(P.coB + base) = cc[idx];
    }
    return;
  }

  // bm == 32: only row 4096 valid
#pragma unroll
  for (int mt = 0; mt < 8; ++mt) {
    int row = m0 + mt * 16 + rq + rho;
    bool act = row <= 4096;
    float x0 = 0.f, x1 = 0.f;
    if (act) {
      if (row < 4096) { x0 = op[2 * row]; x1 = op[2 * row + 1]; }
      else            { x0 = tp[0];       x1 = tp[1]; }
    }
#pragma unroll
    for (int nt = 0; nt < 4; ++nt) {
      f32x4 v = acc[mt][nt];
      float own = sel4(v, rho);
      float r1  = __shfl_xor(sel4(v, rho ^ 1), 1, 64);
      float r2  = __shfl_xor(sel4(v, rho ^ 2), 2, 64);
      float r3  = __shfl_xor(sel4(v, rho ^ 3), 3, 64);
      float g0 = pick(rho,     own, r1, r2, r3);
      float g1 = pick(rho ^ 1, own, r1, r2, r3);
      float g2 = pick(rho ^ 2, own, r1, r2, r3);
      float g3 = pick(rho ^ 3, own, r1, r2, r3);
      if (act) {
        float4 bs = bsv[nt], w0 = w0v[nt], w1 = w1v[nt];
        float p0 = g0 + bs.x + w0.x * x0 + w1.x * x1;
        float p1 = g1 + bs.y + w0.y * x0 + w1.y * x1;
        float p2 = g2 + bs.z + w0.z * x0 + w1.z * x1;
        float p3 = g3 + bs.w + w0.w * x0 + w1.w * x1;
        int u = uu[nt];
        size_t ci = (size_t)row * 512 + u;
        float c_old = (float)P.coB[ci];
        float ii = sigm(p0), ff = sigm(p1), gg = tanh_f(p2), oo = sigm(p3);
        float cn = ff * c_old + ii * gg;
        float h  = oo * tanh_f(cn);
        P.coB[ci] = (__bf16)cn;
        An[ci] = (__bf16)h;
        if (row == 4096) htn[u] = h;
      }
    }
  }
}

// ---------------------------------------------------------------------------
// Attention for step p, task b (64 tasks x 64 rows) + last-done finalize.
// ---------------------------------------------------------------------------
__device__ void do_att(const SP& P, int p, int b)
{
  __shared__ __align__(16) float qs[512];
  __shared__ float red[256];
  __shared__ float red2[256];
  __shared__ float es[64];
  __shared__ unsigned int sOld;
  const int t = threadIdx.x;
  const __bf16* Zb = (p & 1) ? P.Zb1 : P.Zb0;
  const float* qv  = (p & 1) ? P.q1 : P.q0;
  const float* ht  = P.ht + (size_t)p * 512;

  for (int c = t; c < 512; c += 256) qs[c] = qv[c];
  __syncthreads();

  const int r0 = b * 64, rl = t >> 2, p4 = t & 3;
  const bf16x8* krow = (const bf16x8*)(Zb + (size_t)(r0 + rl) * 1024);
  float a = 0.f;
  for (int i = p4; i < 64; i += 4) {
    bf16x8 kk = krow[i];
    const float* qq = qs + i * 8;
#pragma unroll
    for (int j = 0; j < 8; ++j) a += (float)kk[j] * qq[j];
  }
  red[t] = a;
  __syncthreads();
  if (t < 64)
    es[t] = __expf((red[4 * t] + red[4 * t + 1] + red[4 * t + 2] + red[4 * t + 3]) *
                   0.04419417382415922f);
  __syncthreads();

  float s0 = 0.f, s1 = 0.f;
  for (int r = 0; r < 64; ++r) {
    const __bf16* vr = Zb + (size_t)(r0 + r) * 1024 + 512;
    float e = es[r];
    s0 += e * (float)vr[t];
    s1 += e * (float)vr[t + 256];
  }
  P.part[b * 513 + t] = s0;
  P.part[b * 513 + 256 + t] = s1;
  if (t == 0) {
    float se = 0.f;
#pragma unroll
    for (int r = 0; r < 64; ++r) se += es[r];
    P.part[b * 513 + 512] = se;
  }
  __threadfence();
  __syncthreads();
  if (t == 0) sOld = atomicAdd(P.cnt, 1u);
  __syncthreads();
  if (sOld == 63) {
    __threadfence();
    float s = 0.f, s2 = 0.f, se = 0.f;
    for (int bb = 0; bb < 64; ++bb) {
      s  += P.part[bb * 513 + t];
      s2 += P.part[bb * 513 + 256 + t];
      se += P.part[bb * 513 + 512];
    }
    float inv = 1.f / se;
    float va = ht[t] + s * inv + P.scene[t];
    float vb = ht[t + 256] + s2 * inv + P.scene[t + 256];
    red[t]  = va * P.out_w[t]       + vb * P.out_w[t + 256];
    red2[t] = va * P.out_w[512 + t] + vb * P.out_w[768 + t];
    __syncthreads();
    for (int st = 128; st > 0; st >>= 1) {
      if (t < st) { red[t] += red[t + st]; red2[t] += red2[t + st]; }
      __syncthreads();
    }
    if (t == 0) {
      P.out[2 * p]     = red[0]  + P.out_b[0];
      P.out[2 * p + 1] = red2[0] + P.out_b[1];
      *P.cnt = 0;
    }
  }
}

// ---------------------------------------------------------------------------
// Step dispatch: 458 blocks (R13 decode).
// ---------------------------------------------------------------------------
__global__ __launch_bounds__(256, 2) void step_kernel(SP P, int p)
{
  const int b = blockIdx.x;
  if (b < 384) {
    int x = b & 7, s = b >> 3;
    do_gemm(P, p, x + 8 * (s / 12), s % 12);
  } else if (b < 448) {
    int x = b & 7, idx = (b >> 3) - 48;
    int a = 2 * (x + 8 * (idx >> 1)) + (idx & 1);
    if (p >= 1) do_att(P, p - 1, a);
  } else {
    int ti = b - 448;
    int bn = (ti < 8) ? ti : (12 + (ti - 8));
    do_gemm(P, p, 32, bn);
  }
}

__global__ __launch_bounds__(256) void att_step(SP P, int p) {
  do_att(P, p, blockIdx.x);
}

// ---------------------------------------------------------------------------
// Prep kernels (unchanged).
// ---------------------------------------------------------------------------
__global__ __launch_bounds__(256) void init_state(
    const float* __restrict__ others0, const float* __restrict__ target0,
    const float* __restrict__ w_ih, const float* __restrict__ b_ih,
    const float* __restrict__ b_hh,
    __bf16* __restrict__ coB, __bf16* __restrict__ A0, float* __restrict__ ht0,
    unsigned int* __restrict__ cnt)
{
  int g = blockIdx.x * 256 + threadIdx.x;
  if (g == 0) *cnt = 0u;
  if (g >= 4097 * 512) return;
  int r = g >> 9, j = g & 511;
  float x0, x1;
  if (r < 4096) { x0 = others0[2 * r]; x1 = others0[2 * r + 1]; }
  else          { x0 = target0[0];     x1 = target0[1]; }
  float pre[4];
#pragma unroll
  for (int gg = 0; gg < 4; ++gg) {
    int n = gg * 512 + j;
    pre[gg] = b_ih[n] + b_hh[n] + w_ih[2 * n] * x0 + w_ih[2 * n + 1] * x1;
  }
  float cn = sigm(pre[0]) * tanh_f(pre[2]);
  float h  = sigm(pre[3]) * tanh_f(cn);
  coB[g] = (__bf16)cn;
  A0[g] = (__bf16)h;
  if (r == 4096) ht0[j] = h;
}

__global__ __launch_bounds__(256) void pack_w(
    const float* __restrict__ w_hh, const float* __restrict__ wk,
    const float* __restrict__ wv,   const float* __restrict__ wq,
    __bf16* __restrict__ Wp)
{
  int o = blockIdx.x * 256 + threadIdx.x;   // 1,835,008
  int j = o & 7, nn = (o >> 3) & 15, kg = (o >> 7) & 63, ntg = o >> 13;
  int n = ntg * 16 + nn, k = kg * 8 + j;
  float v;
  if (n < 2048)      { int u = n >> 2, g = n & 3; v = w_hh[(g * 512 + u) * 512 + k]; }
  else if (n < 2560) v = wk[(n - 2048) * 512 + k];
  else if (n < 3072) v = wv[(n - 2560) * 512 + k];
  else               v = wq[(n - 3072) * 512 + k];
  Wp[o] = (__bf16)v;
}

__global__ __launch_bounds__(256) void pack_misc(
    const float* __restrict__ b_ih, const float* __restrict__ b_hh,
    const float* __restrict__ w_ih,
    const float* __restrict__ bk, const float* __restrict__ bv,
    const float* __restrict__ bq,
    float* __restrict__ bs, float* __restrict__ w0, float* __restrict__ w1,
    float* __restrict__ biasz)
{
  int i = blockIdx.x * 256 + threadIdx.x;
  if (i < 2048) {
    int u = i >> 2, g = i & 3, n = g * 512 + u;
    bs[i] = b_ih[n] + b_hh[n];
    w0[i] = w_ih[2 * n];
    w1[i] = w_ih[2 * n + 1];
  } else if (i < 2048 + 1536) {
    int z = i - 2048;
    biasz[z] = (z < 512) ? bk[z] : (z < 1024 ? bv[z - 512] : bq[z - 1024]);
  }
}

__global__ __launch_bounds__(256) void scene1_kernel(
    const int* __restrict__ map, const float* __restrict__ emb,
    const float* __restrict__ w1, const float* __restrict__ b1,
    float* __restrict__ out1)
{
  __shared__ float wl[576];
  __shared__ float bl[16];
  const int t = threadIdx.x;
  for (int i = t; i < 576; i += 256) wl[i] = w1[i];
  if (t < 16) bl[t] = b1[t];
  __syncthreads();
  const int y = blockIdx.x, x = t;
  float nb[4][9];
#pragma unroll
  for (int dy = 0; dy < 3; ++dy)
#pragma unroll
    for (int dx = 0; dx < 3; ++dx) {
      int yy = y + dy - 1, xx = x + dx - 1;
      bool ok = (yy >= 0 && yy < 256 && xx >= 0 && xx < 256);
      int m = ok ? map[yy * 256 + xx] : 0;
#pragma unroll
      for (int c = 0; c < 4; ++c)
        nb[c][dy * 3 + dx] = ok ? emb[m * 4 + c] : 0.f;
    }
  for (int oc = 0; oc < 16; ++oc) {
    float a = bl[oc];
#pragma unroll
    for (int c = 0; c < 4; ++c)
#pragma unroll
      for (int k = 0; k < 9; ++k) a += wl[(oc * 4 + c) * 9 + k] * nb[c][k];
    out1[oc * 65536 + y * 256 + x] = fmaxf(a, 0.f);
  }
}

__global__ __launch_bounds__(256) void scene2_kernel(
    const float* __restrict__ out1, const float* __restrict__ w2,
    const float* __restrict__ b2, float* __restrict__ rowpart)
{
  __shared__ float wl[1152];
  __shared__ float lds4[4 * 8];
  const int t = threadIdx.x;
  const int y = blockIdx.x & 255, ocg = blockIdx.x >> 8;
  for (int i = t; i < 1152; i += 256) wl[i] = w2[ocg * 1152 + i];
  __syncthreads();
  const int x = t;
  float acc[8];
#pragma unroll
  for (int o = 0; o < 8; ++o) acc[o] = b2[ocg * 8 + o];
  for (int ic = 0; ic < 16; ++ic) {
    float nb[9];
#pragma unroll
    for (int dy = 0; dy < 3; ++dy)
#pragma unroll
      for (int dx = 0; dx < 3; ++dx) {
        int yy = y + dy - 1, xx = x + dx - 1;
        bool ok = (yy >= 0 && yy < 256 && xx >= 0 && xx < 256);
        nb[dy * 3 + dx] = ok ? out1[ic * 65536 + yy * 256 + xx] : 0.f;
      }
#pragma unroll
    for (int o = 0; o < 8; ++o) {
      const float* w = &wl[(o * 16 + ic) * 9];
#pragma unroll
      for (int k = 0; k < 9; ++k) acc[o] += w[k] * nb[k];
    }
  }
  const int wave = t >> 6, lane = t & 63;
#pragma unroll
  for (int o = 0; o < 8; ++o) {
    float v = fmaxf(acc[o], 0.f);
#pragma unroll
    for (int m = 1; m < 64; m <<= 1) v += __shfl_xor(v, m, 64);
    if (lane == 0) lds4[wave * 8 + o] = v;
  }
  __syncthreads();
  if (t < 8)
    rowpart[y * 32 + ocg * 8 + t] = lds4[t] + lds4[8 + t] + lds4[16 + t] + lds4[24 + t];
}

__global__ __launch_bounds__(512) void scene3_kernel(
    const float* __restrict__ rowpart, const float* __restrict__ fcw,
    const float* __restrict__ fcb, float* __restrict__ scene)
{
  __shared__ float mean[32];
  const int t = threadIdx.x;
  if (t < 32) {
    float s = 0.f;
    for (int y = 0; y < 256; ++y) s += rowpart[y * 32 + t];
    mean[t] = s * (1.f / 65536.f);
  }
  __syncthreads();
  float a = fcb[t];
#pragma unroll
  for (int c = 0; c < 32; ++c) a += mean[c] * fcw[t * 32 + c];
  scene[t] = a;
}

// ---------------------------------------------------------------------------
extern "C" void kernel_launch(void* const* d_in, const int* in_sizes, int n_in,
                              void* d_out, int out_size, void* d_ws, size_t ws_size,
                              hipStream_t stream) {
  const float* target    = (const float*)d_in[0];
  const float* others    = (const float*)d_in[1];
  const int*   scene_map = (const int*)d_in[2];
  const float* emb       = (const float*)d_in[3];
  const float* c1w       = (const float*)d_in[4];
  const float* c1b       = (const float*)d_in[5];
  const float* c2w       = (const float*)d_in[6];
  const float* c2b       = (const float*)d_in[7];
  const float* fcw       = (const float*)d_in[8];
  const float* fcb       = (const float*)d_in[9];
  const float* w_ih      = (const float*)d_in[10];
  const float* w_hh      = (const float*)d_in[11];
  const float* b_ih      = (const float*)d_in[12];
  const float* b_hh      = (const float*)d_in[13];
  const float* wq        = (const float*)d_in[14];
  const float* bq        = (const float*)d_in[15];
  const float* wk        = (const float*)d_in[16];
  const float* bk        = (const float*)d_in[17];
  const float* wv        = (const float*)d_in[18];
  const float* bv        = (const float*)d_in[19];
  const float* out_w     = (const float*)d_in[20];
  const float* out_b     = (const float*)d_in[21];
  float* out = (float*)d_out;

  char* ws = (char*)d_ws;
  size_t off = 0;
  auto alloc = [&](size_t bytes) { size_t o = off; off += (bytes + 255) & ~(size_t)255; return o; };
  __bf16* Zb0   = (__bf16*)(ws + alloc((size_t)4096 * 1024 * 2));
  __bf16* Zb1   = (__bf16*)(ws + alloc((size_t)4096 * 1024 * 2));
  float*  q0    = (float*)(ws + alloc(512 * 4));
  float*  q1    = (float*)(ws + alloc(512 * 4));
  __bf16* Wp    = (__bf16*)(ws + alloc((size_t)1835008 * 2));
  __bf16* A0    = (__bf16*)(ws + alloc((size_t)4224 * 512 * 2));
  __bf16* A1    = (__bf16*)(ws + alloc((size_t)4224 * 512 * 2));
  __bf16* coB   = (__bf16*)(ws + alloc((size_t)4224 * 512 * 2));
  float*  ht    = (float*)(ws + alloc((size_t)65 * 512 * 4));
  float*  scene = (float*)(ws + alloc(2048));
  float*  part  = (float*)(ws + alloc(64 * 513 * 4));
  unsigned int* cnt = (unsigned int*)(ws + alloc(256));
  float*  bs    = (float*)(ws + alloc(2048 * 4));
  float*  w0p   = (float*)(ws + alloc(2048 * 4));
  float*  w1p   = (float*)(ws + alloc(2048 * 4));
  float*  biasz = (float*)(ws + alloc(1536 * 4));
  float*  out1  = (float*)(ws + alloc((size_t)16 * 65536 * 4));
  float*  rowp  = (float*)(ws + alloc(256 * 32 * 4));

  pack_w<<<7168, 256, 0, stream>>>(w_hh, wk, wv, wq, Wp);
  pack_misc<<<14, 256, 0, stream>>>(b_ih, b_hh, w_ih, bk, bv, bq, bs, w0p, w1p, biasz);
  scene1_kernel<<<256, 256, 0, stream>>>(scene_map, emb, c1w, c1b, out1);
  scene2_kernel<<<1024, 256, 0, stream>>>(out1, c2w, c2b, rowp);
  scene3_kernel<<<1, 512, 0, stream>>>(rowp, fcw, fcb, scene);
  init_state<<<8194, 256, 0, stream>>>(others, target, w_ih, b_ih, b_hh, coB, A0, ht, cnt);

  SP hp;
  hp.Wp = (const unsigned short*)Wp;
  hp.A0 = (unsigned short*)A0; hp.A1 = (unsigned short*)A1;
  hp.Zb0 = Zb0; hp.Zb1 = Zb1;
  hp.q0 = q0; hp.q1 = q1;
  hp.coB = coB; hp.ht = ht;
  hp.biasz = biasz;
  hp.bs4 = (const float4*)bs; hp.w04 = (const float4*)w0p; hp.w14 = (const float4*)w1p;
  hp.others = others; hp.target = target;
  hp.scene = scene; hp.out_w = out_w; hp.out_b = out_b;
  hp.part = part; hp.cnt = cnt;
  hp.out = out;

  for (int p = 0; p < 64; ++p)
    step_kernel<<<458, 256, 0, stream>>>(hp, p);
  att_step<<<64, 256, 0, stream>>>(hp, 63);
}